// Round 13
// baseline (100.390 us; speedup 1.0000x reference)
//
#include <hip/hip_runtime.h>
#include <math.h>

// Problem constants (from reference setup_inputs)
#define B_     256
#define V_     50
#define C_     32
#define E_     128
#define VOCAB_ 100000
#define L_     (V_ * C_)      // 1600 flattened codes per patient
#define SPB    8              // blocks per patient
#define NCHUNK (SPB * 4)      // bag wave-chunks per patient (32) -> chunk <= 50
#define NBLK   (B_ * SPB)     // 2048 blocks
#define MAXB   13             // max batches per wave chunk: ceil(50/4)

// R13: kill the serial-round bottleneck. The bag loop previously had a
// RUNTIME trip count -> compiler emits per-iteration vmcnt(0) drains ->
// ~13 serial full-latency rounds/wave (~35us under load). This explains
// every null result (bytes/warmth/lines/atomics made no difference because
// round count was the limiter). Now: compile-time MAXB batches, fully
// unrolled; all batch codes precomputed from registers; ALL <=26 row loads
// issued back-to-back into a register array (wave-uniform k<nb guards);
// consumption afterwards. Whole chunk in flight at once.
// Epilogue: plain partial stores + tiny reduce kernel (no atomics, R12).
__global__ __launch_bounds__(256, 3) void fused_kernel(
    const float* __restrict__ W,      // [VOCAB, E]
    const int*   __restrict__ codes,  // [B, V, C]
    const int*   __restrict__ nvis,   // [B]
    float*       __restrict__ out,    // [B, V, E]
    float*       __restrict__ part)   // [B_, SPB, E] partials in d_ws
{
    const int tid  = threadIdx.x;
    const int wave = tid >> 6;
    const int lane = tid & 63;
    const int g    = lane >> 4;       // row group within wave [0,4)
    const int l4   = lane & 15;       // lane within group

    const int b  = blockIdx.x >> 3;        // / SPB
    const int s  = blockIdx.x & (SPB - 1);
    const int nv = nvis[b];
    const int* cf = codes + b * L_;
    float* ob = out + (size_t)b * V_ * E_;

    // ---- singles + pads: one output row per (wave,group); i = k*8+s ----
    {
        const int i = (wave * 4 + g) * SPB + s;    // unique cover of [0,128)
        if (i < V_ - 1) {
            if (i < nv - 1) {
                const int code = cf[i];
                const float* row = W + (size_t)code * E_;
                float4 v1 = ((const float4*)row)[l4];
                float4 v2 = ((const float4*)row)[16 + l4];
                float ss = v1.x*v1.x + v1.y*v1.y + v1.z*v1.z + v1.w*v1.w
                         + v2.x*v2.x + v2.y*v2.y + v2.z*v2.z + v2.w*v2.w;
                #pragma unroll
                for (int m = 1; m <= 8; m <<= 1) ss += __shfl_xor(ss, m, 64);
                const float sc = fminf(1.0f, 1.0f / fmaxf(sqrtf(ss), 1e-12f));
                float* orow = ob + (size_t)(V_ - nv + i) * E_;
                ((float4*)orow)[l4]      = make_float4(v1.x*sc, v1.y*sc, v1.z*sc, v1.w*sc);
                ((float4*)orow)[16 + l4] = make_float4(v2.x*sc, v2.y*sc, v2.z*sc, v2.w*sc);
            } else {
                float* orow = ob + (size_t)(i - (nv - 1)) * E_;
                ((float4*)orow)[l4]      = make_float4(0.f, 0.f, 0.f, 0.f);
                ((float4*)orow)[16 + l4] = make_float4(0.f, 0.f, 0.f, 0.f);
            }
        }
    }

    // ---- bag partial sum: chunk of <= 50 codes, compile-time batches ----
    const int j0    = nv - 1;
    const int j1    = nv * C_;
    const int chunk = (j1 - j0 + NCHUNK - 1) / NCHUNK;   // <= 50
    const int wid   = s * 4 + wave;                      // [0, 32)
    const int a0    = j0 + wid * chunk;
    const int n     = min(a0 + chunk, j1) - a0;          // may be <= 0
    const int nb    = (n + 3) >> 2;                      // batches, <= MAXB

    // batched coalesced code fetch: lane t -> code a0+t (n <= 50 <= 64).
    // Lanes >= n keep cl = 0 -> always a valid row address; masked later.
    int cl = 0;
    if (lane < n) cl = cf[a0 + lane];

    // Stage 1: all batch codes from registers (no memory dependency)
    int codek[MAXB];
    #pragma unroll
    for (int k = 0; k < MAXB; k++)
        codek[k] = __shfl(cl, 4 * k + g, 64);            // 4k+g <= 51 < 64

    // Stage 2: issue ALL row loads back-to-back (wave-uniform guard only)
    float4 va[MAXB], vb[MAXB];
    #pragma unroll
    for (int k = 0; k < MAXB; k++) {
        if (k < nb) {
            const float4* row = (const float4*)(W + (size_t)codek[k] * E_);
            va[k] = row[l4];
            vb[k] = row[16 + l4];
        }
    }

    // Stage 3: consume — norm reduce + masked accumulate per batch
    float4 a1 = make_float4(0.f, 0.f, 0.f, 0.f);
    float4 a2 = make_float4(0.f, 0.f, 0.f, 0.f);
    #pragma unroll
    for (int k = 0; k < MAXB; k++) {
        if (k < nb) {
            float4 v1 = va[k], v2 = vb[k];
            float ss = v1.x*v1.x + v1.y*v1.y + v1.z*v1.z + v1.w*v1.w
                     + v2.x*v2.x + v2.y*v2.y + v2.z*v2.z + v2.w*v2.w;
            #pragma unroll
            for (int m = 1; m <= 8; m <<= 1) ss += __shfl_xor(ss, m, 64);
            float sc = fminf(1.0f, 1.0f / fmaxf(sqrtf(ss), 1e-12f));
            if (4 * k + g >= n) sc = 0.0f;               // tail groups off
            a1.x += v1.x*sc; a1.y += v1.y*sc; a1.z += v1.z*sc; a1.w += v1.w*sc;
            a2.x += v2.x*sc; a2.y += v2.y*sc; a2.z += v2.z*sc; a2.w += v2.w*sc;
        }
    }

    // combine the 4 groups (same col mapping in every group)
    #pragma unroll
    for (int m = 16; m <= 32; m <<= 1) {
        a1.x += __shfl_xor(a1.x, m, 64); a1.y += __shfl_xor(a1.y, m, 64);
        a1.z += __shfl_xor(a1.z, m, 64); a1.w += __shfl_xor(a1.w, m, 64);
        a2.x += __shfl_xor(a2.x, m, 64); a2.y += __shfl_xor(a2.y, m, 64);
        a2.z += __shfl_xor(a2.z, m, 64); a2.w += __shfl_xor(a2.w, m, 64);
    }

    __shared__ float4 s1[4][16], s2[4][16];
    if (lane < 16) { s1[wave][l4] = a1; s2[wave][l4] = a2; }
    __syncthreads();
    // plain coalesced partial store: 32 lanes x float4 = 512B, NO atomics
    if (tid < 32) {
        const int h = tid >> 4;          // 0: cols [0,64), 1: cols [64,128)
        const int q = tid & 15;
        float4 f = (h == 0) ? s1[0][q] : s2[0][q];
        #pragma unroll
        for (int w = 1; w < 4; w++) {
            float4 p = (h == 0) ? s1[w][q] : s2[w][q];
            f.x += p.x; f.y += p.y; f.z += p.z; f.w += p.w;
        }
        ((float4*)(part + (size_t)blockIdx.x * E_))[tid] = f;
    }
}

// Reduce: one block per patient, 128 threads; thread t sums partials over
// s (reads coalesced across threads) and writes bag-row element t.
__global__ __launch_bounds__(128) void reduce_kernel(
    const float* __restrict__ part,   // [B_, SPB, E]
    float*       __restrict__ out)    // [B, V, E]
{
    const int b = blockIdx.x;
    const int t = threadIdx.x;
    const float* p = part + (size_t)b * SPB * E_;
    float acc = 0.0f;
    #pragma unroll
    for (int s = 0; s < SPB; s++) acc += p[s * E_ + t];
    out[((size_t)b * V_ + (V_ - 1)) * E_ + t] = acc;
}

extern "C" void kernel_launch(void* const* d_in, const int* in_sizes, int n_in,
                              void* d_out, int out_size, void* d_ws, size_t ws_size,
                              hipStream_t stream) {
    const float* W     = (const float*)d_in[0];
    const int*   codes = (const int*)d_in[1];
    const int*   nvis  = (const int*)d_in[2];
    float*       out   = (float*)d_out;
    float*       part  = (float*)d_ws;   // B_*SPB*E_*4 = 1 MB scratch

    fused_kernel<<<NBLK, 256, 0, stream>>>(W, codes, nvis, out, part);
    reduce_kernel<<<B_, 128, 0, stream>>>(part, out);
}